// Round 3
// baseline (50908.142 us; speedup 1.0000x reference)
//
#include <hip/hip_runtime.h>

#define BB 32
#define TT 512
#define SS 1024
#define HH 512
#define MM 16

// d_ws layout (bytes):
//   [0, 2048)    : unsigned slots[512]   (aslots[256] @0, bslots[32] @256)
//   [2048, +64K) : float ctx_st[32][512]
//   [+64K, +128K): float h_st[2][32][512]

__device__ __forceinline__ float sigm(float z) { return 1.f / (1.f + __expf(-z)); }

__device__ __forceinline__ void stg_agent(float* p, float v) {
  __hip_atomic_store(p, v, __ATOMIC_RELAXED, __HIP_MEMORY_SCOPE_AGENT);
}

__device__ __forceinline__ void fma4(float& a, const float4& u, const float4& v) {
  a = fmaf(u.x, v.x, fmaf(u.y, v.y, fmaf(u.z, v.z, fmaf(u.w, v.w, a))));
}

__global__ void k_init(float* __restrict__ out_align, float* __restrict__ ctx_st,
                       float* __restrict__ h_st, unsigned* __restrict__ slots) {
  const size_t idx = (size_t)blockIdx.x * blockDim.x + threadIdx.x;
  const size_t stride = (size_t)gridDim.x * blockDim.x;
  const float4 z4 = make_float4(0.f, 0.f, 0.f, 0.f);
  float4* a4 = (float4*)out_align;
  const size_t n4 = (size_t)BB * TT * SS / 4;
  for (size_t i = idx; i < n4; i += stride) a4[i] = z4;
  if (idx < (size_t)BB * HH / 4) ((float4*)ctx_st)[idx] = z4;
  if (idx < (size_t)2 * BB * HH / 4) ((float4*)h_st)[idx] = z4;
  if (idx < 512) slots[idx] = 0u;
}

__launch_bounds__(512, 1)
__global__ void k_main(const float* __restrict__ input, const float* __restrict__ memory,
                       const float* __restrict__ Wih, const float* __restrict__ Whh,
                       const float* __restrict__ bih, const float* __restrict__ bhh,
                       const float* __restrict__ Wg, const float* __restrict__ bgv,
                       float* __restrict__ out_ctx, float* __restrict__ out_align,
                       float* __restrict__ ctx_st, float* __restrict__ h_st,
                       unsigned* __restrict__ slots) {
  __shared__ float ctx_lds[16 * HH];   // 32 KB: ctx for this block's 16 batches
  __shared__ float h_lds[16 * HH];     // 32 KB: h   for this block's 16 batches
  __shared__ float gbuf[16 * 17];
  __shared__ float bias_s[16];
  __shared__ float c_s[64];
  __shared__ float h_s[HH];
  __shared__ float phi_s[48];
  __shared__ float alpha_s[MM], beta_s[MM], rbeta_s[MM], ksi_s[MM];
  __shared__ float w_s[SS];
  __shared__ int win_s[2];

  const int tid = threadIdx.x;
  const int bid = blockIdx.x;
  const int bhalf = bid & 1;   // which 16 batches
  const int jt = bid >> 1;     // h-col group: cols [4jt,4jt+4) of each gate
  const int B0 = bhalf * 16;

  unsigned* aslots = slots;
  unsigned* bslots = slots + 256;

  // GEMM thread coords: full-K split by 32
  const int ks = tid & 31;            // k-split 0..31
  const int rb = tid >> 5;            // 0..15
  const int rg = rb >> 2;             // gate 0..3
  const int bg = rb & 3;              // batch group (4 batches)

  const float* wih_r0 = Wih + (size_t)(rg * HH + jt * 4 + 0) * 1024;
  const float* wih_r1 = Wih + (size_t)(rg * HH + jt * 4 + 1) * 1024;
  const float* wih_r2 = Wih + (size_t)(rg * HH + jt * 4 + 2) * 1024;
  const float* wih_r3 = Wih + (size_t)(rg * HH + jt * 4 + 3) * 1024;
  const float* whh_r0 = Whh + (size_t)(rg * HH + jt * 4 + 0) * HH;
  const float* whh_r1 = Whh + (size_t)(rg * HH + jt * 4 + 1) * HH;
  const float* whh_r2 = Whh + (size_t)(rg * HH + jt * 4 + 2) * HH;
  const float* whh_r3 = Whh + (size_t)(rg * HH + jt * 4 + 3) * HH;

  if (tid < 16) {
    const int g = tid >> 2, jc = tid & 3;
    const int row = g * HH + jt * 4 + jc;
    bias_s[tid] = bih[row] + bhh[row];
  }
  if (tid < 64) c_s[tid] = 0.f;
  if (tid < MM) ksi_s[tid] = 0.f;
  __syncthreads();

  for (int t = 0; t < TT; ++t) {
    const unsigned seq = (unsigned)(t + 1);
    const int par = t & 1;           // h buffer produced at step t-1

    // ---- stage ctx + h(par) for our 16 batches into LDS (batched coherent loads) ----
    {
      const int half = tid >> 8;     // 0: ctx, 1: h
      const int tt2 = tid & 255;
      const unsigned long long* gsrc = (const unsigned long long*)
          (half ? (h_st + ((size_t)par * BB + B0) * HH) : (ctx_st + (size_t)B0 * HH));
      unsigned long long* ldst = (unsigned long long*)(half ? h_lds : ctx_lds);
      unsigned long long tmp[16];
#pragma unroll
      for (int i = 0; i < 16; ++i)
        tmp[i] = __hip_atomic_load(gsrc + tt2 + i * 256, __ATOMIC_RELAXED,
                                   __HIP_MEMORY_SCOPE_AGENT);
#pragma unroll
      for (int i = 0; i < 16; ++i) ldst[tt2 + i * 256] = tmp[i];
    }
    __syncthreads();

    // ---- Phase A: gates GEMM (M=16,N=16,K=1536) + LSTM cell ----
    {
      float acc[4][4];
#pragma unroll
      for (int i2 = 0; i2 < 4; ++i2)
#pragma unroll
        for (int j = 0; j < 4; ++j) acc[i2][j] = 0.f;

      const float* xrow0 = input + ((size_t)(B0 + bg * 4 + 0) * TT + t) * HH;
      const float* xrow1 = input + ((size_t)(B0 + bg * 4 + 1) * TT + t) * HH;
      const float* xrow2 = input + ((size_t)(B0 + bg * 4 + 2) * TT + t) * HH;
      const float* xrow3 = input + ((size_t)(B0 + bg * 4 + 3) * TT + t) * HH;

      // x region: W_ih[:, 0:512]
#pragma unroll
      for (int q = 0; q < 4; ++q) {
        const int k = 4 * ks + 128 * q;
        const float4 w0 = *(const float4*)(wih_r0 + k);
        const float4 w1 = *(const float4*)(wih_r1 + k);
        const float4 w2 = *(const float4*)(wih_r2 + k);
        const float4 w3 = *(const float4*)(wih_r3 + k);
        float4 xv;
        xv = *(const float4*)(xrow0 + k);
        fma4(acc[0][0], xv, w0); fma4(acc[0][1], xv, w1); fma4(acc[0][2], xv, w2); fma4(acc[0][3], xv, w3);
        xv = *(const float4*)(xrow1 + k);
        fma4(acc[1][0], xv, w0); fma4(acc[1][1], xv, w1); fma4(acc[1][2], xv, w2); fma4(acc[1][3], xv, w3);
        xv = *(const float4*)(xrow2 + k);
        fma4(acc[2][0], xv, w0); fma4(acc[2][1], xv, w1); fma4(acc[2][2], xv, w2); fma4(acc[2][3], xv, w3);
        xv = *(const float4*)(xrow3 + k);
        fma4(acc[3][0], xv, w0); fma4(acc[3][1], xv, w1); fma4(acc[3][2], xv, w2); fma4(acc[3][3], xv, w3);
      }
      // ctx region: W_ih[:, 512:1024], ctx from LDS
#pragma unroll
      for (int q = 0; q < 4; ++q) {
        const int k = 4 * ks + 128 * q;
        const float4 w0 = *(const float4*)(wih_r0 + 512 + k);
        const float4 w1 = *(const float4*)(wih_r1 + 512 + k);
        const float4 w2 = *(const float4*)(wih_r2 + 512 + k);
        const float4 w3 = *(const float4*)(wih_r3 + 512 + k);
        float4 xv;
        xv = *(const float4*)(ctx_lds + (bg * 4 + 0) * HH + k);
        fma4(acc[0][0], xv, w0); fma4(acc[0][1], xv, w1); fma4(acc[0][2], xv, w2); fma4(acc[0][3], xv, w3);
        xv = *(const float4*)(ctx_lds + (bg * 4 + 1) * HH + k);
        fma4(acc[1][0], xv, w0); fma4(acc[1][1], xv, w1); fma4(acc[1][2], xv, w2); fma4(acc[1][3], xv, w3);
        xv = *(const float4*)(ctx_lds + (bg * 4 + 2) * HH + k);
        fma4(acc[2][0], xv, w0); fma4(acc[2][1], xv, w1); fma4(acc[2][2], xv, w2); fma4(acc[2][3], xv, w3);
        xv = *(const float4*)(ctx_lds + (bg * 4 + 3) * HH + k);
        fma4(acc[3][0], xv, w0); fma4(acc[3][1], xv, w1); fma4(acc[3][2], xv, w2); fma4(acc[3][3], xv, w3);
      }
      // h region: W_hh, h from LDS
#pragma unroll
      for (int q = 0; q < 4; ++q) {
        const int k = 4 * ks + 128 * q;
        const float4 w0 = *(const float4*)(whh_r0 + k);
        const float4 w1 = *(const float4*)(whh_r1 + k);
        const float4 w2 = *(const float4*)(whh_r2 + k);
        const float4 w3 = *(const float4*)(whh_r3 + k);
        float4 xv;
        xv = *(const float4*)(h_lds + (bg * 4 + 0) * HH + k);
        fma4(acc[0][0], xv, w0); fma4(acc[0][1], xv, w1); fma4(acc[0][2], xv, w2); fma4(acc[0][3], xv, w3);
        xv = *(const float4*)(h_lds + (bg * 4 + 1) * HH + k);
        fma4(acc[1][0], xv, w0); fma4(acc[1][1], xv, w1); fma4(acc[1][2], xv, w2); fma4(acc[1][3], xv, w3);
        xv = *(const float4*)(h_lds + (bg * 4 + 2) * HH + k);
        fma4(acc[2][0], xv, w0); fma4(acc[2][1], xv, w1); fma4(acc[2][2], xv, w2); fma4(acc[2][3], xv, w3);
        xv = *(const float4*)(h_lds + (bg * 4 + 3) * HH + k);
        fma4(acc[3][0], xv, w0); fma4(acc[3][1], xv, w1); fma4(acc[3][2], xv, w2); fma4(acc[3][3], xv, w3);
      }

      // ks-reduction: in-wave xor butterfly over lane bits 0..4 (ks = lane&31)
      const int lane = tid & 63;
#pragma unroll
      for (int a = 0; a < 16; ++a) {
        float v = acc[a >> 2][a & 3];
        v += __shfl_xor(v, 1, 64);
        v += __shfl_xor(v, 2, 64);
        v += __shfl_xor(v, 4, 64);
        v += __shfl_xor(v, 8, 64);
        v += __shfl_xor(v, 16, 64);
        if ((lane & 31) == 0)
          gbuf[(bg * 4 + (a >> 2)) * 17 + (rg * 4 + (a & 3))] = v + bias_s[rg * 4 + (a & 3)];
      }
      __syncthreads();
      if (tid < 64) {
        const int bl = tid >> 2, jc = tid & 3;
        const float ig = gbuf[bl * 17 + jc];
        const float fg = gbuf[bl * 17 + 4 + jc];
        const float gg = gbuf[bl * 17 + 8 + jc];
        const float og = gbuf[bl * 17 + 12 + jc];
        float c = sigm(fg) * c_s[tid] + sigm(ig) * tanhf(gg);
        c_s[tid] = c;
        const float h = sigm(og) * tanhf(c);
        float* hw = h_st + ((size_t)((t + 1) & 1) * BB) * HH;
        stg_agent(hw + (size_t)(B0 + bl) * HH + jt * 4 + jc, h);
      }
    }

    // ---- post phase-A ----
    __threadfence_block();
    __syncthreads();
    if (tid == 0)
      __hip_atomic_store(&aslots[bid], seq, __ATOMIC_RELEASE, __HIP_MEMORY_SCOPE_AGENT);

    // ---- Phase B (blocks 0..31 only): phi, window, ctx ----
    if (bid < BB) {
      const int b = bid;
      if (tid < 256) {
        while (__hip_atomic_load(&aslots[tid], __ATOMIC_RELAXED, __HIP_MEMORY_SCOPE_AGENT) < seq)
          __builtin_amdgcn_s_sleep(1);
      }
      __syncthreads();

      const float* hb = h_st + ((size_t)((t + 1) & 1) * BB + b) * HH;
      h_s[tid] = __hip_atomic_load(hb + tid, __ATOMIC_RELAXED, __HIP_MEMORY_SCOPE_AGENT);
      __syncthreads();

      // phi = h @ Wg^T + bg : 8 waves x 6 rows
      {
        const int wv2 = tid >> 6, lane2 = tid & 63;
#pragma unroll
        for (int e = 0; e < 6; ++e) {
          const int r = wv2 * 6 + e;
          const float* wr = Wg + (size_t)r * HH + lane2;
          const float* hp = h_s + lane2;
          float p = 0.f;
#pragma unroll
          for (int j2 = 0; j2 < 8; ++j2) p = fmaf(hp[j2 * 64], wr[j2 * 64], p);
          p += __shfl_xor(p, 32, 64); p += __shfl_xor(p, 16, 64);
          p += __shfl_xor(p, 8, 64);  p += __shfl_xor(p, 4, 64);
          p += __shfl_xor(p, 2, 64);  p += __shfl_xor(p, 1, 64);
          if (lane2 == 0) phi_s[r] = p + bgv[r];
        }
      }
      __syncthreads();
      if (tid < MM) {
        ksi_s[tid] += __expf(phi_s[tid]);
        beta_s[tid] = __expf(phi_s[MM + tid]);
      }
      __syncthreads();
      if (tid == 0) {
        float mx = -1e30f;
        for (int m = 0; m < MM; ++m) mx = fmaxf(mx, phi_s[2 * MM + m]);
        float ssum = 0.f; float ev[MM];
        for (int m = 0; m < MM; ++m) { ev[m] = __expf(phi_s[2 * MM + m] - mx); ssum += ev[m]; }
        const float inv = 1.f / ssum;
        float lo = 1e30f, hi = -1e30f;
        for (int m = 0; m < MM; ++m) {
          alpha_s[m] = ev[m] * inv;
          rbeta_s[m] = 1.f / beta_s[m];
          const float dd = 13.f * beta_s[m] + 3.f;
          lo = fminf(lo, ksi_s[m] - dd);
          hi = fmaxf(hi, ksi_s[m] + dd);
        }
        int ilo = (int)floorf(lo); if (ilo < 0) ilo = 0; if (ilo > SS) ilo = SS;
        int ihi = (int)ceilf(hi) + 1; if (ihi > SS) ihi = SS; if (ihi < ilo) ihi = ilo;
        win_s[0] = ilo; win_s[1] = ihi;
      }
      __syncthreads();
      const int ilo = win_s[0], ihi = win_s[1];
      float* arow = out_align + ((size_t)b * TT + t) * SS;
      for (int s = ilo + tid; s < ihi; s += 512) {
        const float us = (float)s;
        float wsum = 0.f;
#pragma unroll
        for (int m = 0; m < MM; ++m) {
          const float rb2 = rbeta_s[m];
          const float z1 = (us + 1.5f - ksi_s[m]) * rb2;
          const float z0 = (us + 0.5f - ksi_s[m]) * rb2;
          wsum += alpha_s[m] * (sigm(z1) - sigm(z0));
        }
        w_s[s - ilo] = wsum;
        arow[s] = wsum;
      }
      __syncthreads();
      {
        const int d = tid;
        float acc3 = 0.f;
        const float* mp = memory + ((size_t)b * SS + ilo) * HH + d;
        int s = ilo;
        for (; s + 4 <= ihi; s += 4, mp += 4 * HH) {
          const float m0 = mp[0], m1 = mp[HH], m2 = mp[2 * HH], m3 = mp[3 * HH];
          acc3 = fmaf(w_s[s - ilo + 0], m0, acc3);
          acc3 = fmaf(w_s[s - ilo + 1], m1, acc3);
          acc3 = fmaf(w_s[s - ilo + 2], m2, acc3);
          acc3 = fmaf(w_s[s - ilo + 3], m3, acc3);
        }
        for (; s < ihi; ++s, mp += HH) acc3 = fmaf(w_s[s - ilo], *mp, acc3);
        stg_agent(ctx_st + (size_t)b * HH + d, acc3);
        const size_t o = ((size_t)b * TT + t) * HH + d;
        out_ctx[o] = acc3 + input[o];
      }
      __threadfence_block();
      __syncthreads();
      if (tid == 0)
        __hip_atomic_store(&bslots[bid], seq, __ATOMIC_RELEASE, __HIP_MEMORY_SCOPE_AGENT);
    }

    // ---- everyone waits for phase B (ctx ready) ----
    if (tid < 32) {
      while (__hip_atomic_load(&bslots[tid], __ATOMIC_RELAXED, __HIP_MEMORY_SCOPE_AGENT) < seq)
        __builtin_amdgcn_s_sleep(1);
    }
    __syncthreads();
  }
}

extern "C" void kernel_launch(void* const* d_in, const int* in_sizes, int n_in,
                              void* d_out, int out_size, void* d_ws, size_t ws_size,
                              hipStream_t stream) {
  const float* input = (const float*)d_in[0];
  const float* memory = (const float*)d_in[1];
  const float* Wih = (const float*)d_in[2];
  const float* Whh = (const float*)d_in[3];
  const float* bih = (const float*)d_in[4];
  const float* bhh = (const float*)d_in[5];
  const float* Wg = (const float*)d_in[6];
  const float* bgv = (const float*)d_in[7];
  float* out_ctx = (float*)d_out;
  float* out_align = out_ctx + (size_t)BB * TT * HH;
  unsigned* slots = (unsigned*)d_ws;
  float* ctx_st = (float*)((char*)d_ws + 2048);
  float* h_st = (float*)((char*)d_ws + 2048 + (size_t)BB * HH * 4);

  k_init<<<dim3(2048), dim3(256), 0, stream>>>(out_align, ctx_st, h_st, slots);

  void* args[] = { (void*)&input, (void*)&memory, (void*)&Wih, (void*)&Whh,
                   (void*)&bih, (void*)&bhh, (void*)&Wg, (void*)&bgv,
                   (void*)&out_ctx, (void*)&out_align,
                   (void*)&ctx_st, (void*)&h_st, (void*)&slots };
  hipLaunchCooperativeKernel((void*)k_main, dim3(256), dim3(512), args, 0, stream);
}

// Round 4
// 10827.855 us; speedup vs baseline: 4.7016x; 4.7016x over previous
//
#include <hip/hip_runtime.h>

#define BB 32
#define TT 512
#define SS 1024
#define HH 512
#define MM 16

typedef float f4 __attribute__((ext_vector_type(4)));

// d_ws layout (bytes)  — total ~6.24 MB
#define WS_ASLOTS 0          // 256 u32 (8 groups x 32)
#define WS_BSLOTS 1024       // 128 u32 (8 groups x 16)
#define WS_CTX    2048       // 32*512 f32  (64 KB)
#define WS_H      67584      // 2*32*512 f32 (128 KB)
#define WS_WIHB   198656     // 2048*1024 bf16 (4 MB)
#define WS_WHHB   4392960    // 2048*512 bf16 (2 MB)
#define WS_WGB    6490112    // 48*512 bf16 (48 KB)

// padded LDS layouts (pad 4 floats per k-chunk to spread bank groups)
#define XCS 1152             // 1024 + 4*32
#define HS  640              // 512 + 4*32
#define IDX(k)  ((k) + (((k) >> 5) << 2))
#define IDXH(k) ((k) + (((k) >> 4) << 2))

__device__ __forceinline__ float sigm(float z) { return 1.f / (1.f + __expf(-z)); }
__device__ __forceinline__ float bf2f(unsigned short u) {
  return __uint_as_float((unsigned)u << 16);
}
__device__ __forceinline__ unsigned short f2bf(float f) {
  unsigned u = __float_as_uint(f);
  return (unsigned short)((u + 0x7fffu + ((u >> 16) & 1u)) >> 16);
}
__device__ __forceinline__ void fma4(float& a, const f4& u, const f4& v) {
  a = fmaf(u.x, v.x, fmaf(u.y, v.y, fmaf(u.z, v.z, fmaf(u.w, v.w, a))));
}

// agent-coherent (LLC) wide loads/stores: bypass L1/L2 like agent-scope atomics,
// but 16B-wide and batched (single vmcnt wait per round).
__device__ __forceinline__ void ld2_sys(const float* p0, const float* p1, f4& a, f4& b) {
  asm volatile("global_load_dwordx4 %0, %2, off sc1\n\t"
               "global_load_dwordx4 %1, %3, off sc1\n\t"
               "s_waitcnt vmcnt(0)"
               : "=&v"(a), "=&v"(b) : "v"(p0), "v"(p1) : "memory");
}
__device__ __forceinline__ void ld1_sys(const float* p0, f4& a) {
  asm volatile("global_load_dwordx4 %0, %1, off sc1\n\ts_waitcnt vmcnt(0)"
               : "=&v"(a) : "v"(p0) : "memory");
}
__device__ __forceinline__ void st_sys(float* p, float v) {
  asm volatile("global_store_dword %0, %1, off sc1" :: "v"(p), "v"(v) : "memory");
}
__device__ __forceinline__ void waitvm0() { asm volatile("s_waitcnt vmcnt(0)" ::: "memory"); }

__global__ void k_init(const float* __restrict__ Wih, const float* __restrict__ Whh,
                       const float* __restrict__ Wg,
                       unsigned short* __restrict__ Wihb, unsigned short* __restrict__ Whhb,
                       unsigned short* __restrict__ Wgb,
                       float* __restrict__ out_align, float* __restrict__ ctx_st,
                       float* __restrict__ h_st, unsigned* __restrict__ slots) {
  const size_t idx = (size_t)blockIdx.x * blockDim.x + threadIdx.x;
  const size_t stride = (size_t)gridDim.x * blockDim.x;
  f4 z4 = {0.f, 0.f, 0.f, 0.f};
  for (size_t i = idx; i < (size_t)BB * TT * SS / 4; i += stride) ((f4*)out_align)[i] = z4;
  for (size_t i = idx; i < (size_t)BB * HH / 4; i += stride) ((f4*)ctx_st)[i] = z4;
  for (size_t i = idx; i < (size_t)2 * BB * HH / 4; i += stride) ((f4*)h_st)[i] = z4;
  for (size_t i = idx; i < 384; i += stride) slots[i] = 0u;
  for (size_t i = idx; i < (size_t)2048 * 1024; i += stride) Wihb[i] = f2bf(Wih[i]);
  for (size_t i = idx; i < (size_t)2048 * 512; i += stride) Whhb[i] = f2bf(Whh[i]);
  for (size_t i = idx; i < (size_t)48 * 512; i += stride) Wgb[i] = f2bf(Wg[i]);
}

__launch_bounds__(512)
__global__ void k_main(const float* __restrict__ input, const float* __restrict__ memory,
                       const float* __restrict__ bih, const float* __restrict__ bhh,
                       const float* __restrict__ bgv,
                       const unsigned short* __restrict__ Wihb,
                       const unsigned short* __restrict__ Whhb,
                       const unsigned short* __restrict__ Wgb,
                       float* __restrict__ out_ctx, float* __restrict__ out_align,
                       float* __restrict__ ctx_st, float* __restrict__ h_st,
                       unsigned* __restrict__ aslots, unsigned* __restrict__ bslots) {
  __shared__ float xc_lds[4 * XCS];    // [b][k'] x|ctx, padded
  __shared__ float h_lds[4 * HS];      // [b][k'] h, padded
  __shared__ float gbuf[16 * 17];      // [b][g][cl]
  __shared__ float bias_s[64];         // [g][cl]
  __shared__ float c_s[64];            // [b][cl] persistent cell state
  __shared__ float h_s[HH];
  __shared__ float w_s[SS];
  __shared__ float red2[4 * 132];
  __shared__ float phi_s[48];
  __shared__ float alpha_s[MM], rbeta_s[MM], ksi_s[MM], beta_s[MM];
  __shared__ int win_s[2];

  const int tid = threadIdx.x;
  const int bid = blockIdx.x;
  const int grp = bid >> 5;        // 8 independent groups of 32 blocks
  const int rB  = bid & 31;        // rank in group -> col slice [16rB,16rB+16)
  const int B0  = grp << 2;        // 4 batches per group

  // phase-A thread coords: 32-way k-split, 16 row-quads (4 gates x 4 col-quads)
  const int ks = tid & 31;
  const int rq = tid >> 5;
  const int gt = rq >> 2;
  const int cq = rq & 3;
  const int colb = (rB << 4) + (cq << 2);
  const unsigned short* wiB = Wihb + (((size_t)(gt << 9) + colb) << 10) + (ks << 5);
  const unsigned short* whB = Whhb + (((size_t)(gt << 9) + colb) << 9) + (ks << 4);

  // phase-B coords: 4 working blocks per batch
  const int bq = rB >> 3;
  const int pp = rB & 7;

  if (tid < 64) {
    const int row = ((tid >> 4) << 9) + (rB << 4) + (tid & 15);
    bias_s[tid] = bih[row] + bhh[row];
    c_s[tid] = 0.f;
  }
  if (tid < MM) ksi_s[tid] = 0.f;
  __syncthreads();

  for (int t = 0; t < TT; ++t) {
    const unsigned seq = (unsigned)(t + 1);
    const int par = t & 1, nxt = par ^ 1;

    // ---- stage x | ctx | h for group's 4 batches into LDS ----
    {
      const int sb = tid >> 7;
      const int sk = (tid & 127) << 2;
      const float* xs = input + (((size_t)(B0 + sb) * TT + t) * HH + sk);
      f4 xv = *(const f4*)xs;
      f4 cv, hv;
      ld2_sys(ctx_st + ((size_t)(B0 + sb) * HH + sk),
              h_st + (((size_t)par * BB) + B0 + sb) * HH + sk, cv, hv);
      *(f4*)&xc_lds[sb * XCS + IDX(sk)] = xv;
      *(f4*)&xc_lds[sb * XCS + IDX(512 + sk)] = cv;
      *(f4*)&h_lds[sb * HS + IDXH(sk)] = hv;
    }
    __syncthreads();

    // ---- Phase A: gates GEMM (4 batches x 16 cols x 4 gates, K=1536) ----
    {
      float acc[4][4] = {{0.f,0.f,0.f,0.f},{0.f,0.f,0.f,0.f},
                         {0.f,0.f,0.f,0.f},{0.f,0.f,0.f,0.f}};  // [row j][batch]
      // W_ih part (k 0..1023: x|ctx)
#pragma unroll
      for (int i = 0; i < 8; ++i) {
        const int kx = 36 * ks + 4 * i;
        f4 xb0 = *(const f4*)&xc_lds[0 * XCS + kx];
        f4 xb1 = *(const f4*)&xc_lds[1 * XCS + kx];
        f4 xb2 = *(const f4*)&xc_lds[2 * XCS + kx];
        f4 xb3 = *(const f4*)&xc_lds[3 * XCS + kx];
#pragma unroll
        for (int j = 0; j < 4; ++j) {
          const uint2 u = *(const uint2*)(wiB + (j << 10) + 4 * i);
          f4 wf;
          wf.x = __uint_as_float(u.x << 16);
          wf.y = __uint_as_float(u.x & 0xffff0000u);
          wf.z = __uint_as_float(u.y << 16);
          wf.w = __uint_as_float(u.y & 0xffff0000u);
          fma4(acc[j][0], xb0, wf); fma4(acc[j][1], xb1, wf);
          fma4(acc[j][2], xb2, wf); fma4(acc[j][3], xb3, wf);
        }
      }
      // W_hh part (k 0..511: h)
#pragma unroll
      for (int i = 0; i < 4; ++i) {
        const int kx = 20 * ks + 4 * i;
        f4 xb0 = *(const f4*)&h_lds[0 * HS + kx];
        f4 xb1 = *(const f4*)&h_lds[1 * HS + kx];
        f4 xb2 = *(const f4*)&h_lds[2 * HS + kx];
        f4 xb3 = *(const f4*)&h_lds[3 * HS + kx];
#pragma unroll
        for (int j = 0; j < 4; ++j) {
          const uint2 u = *(const uint2*)(whB + (j << 9) + 4 * i);
          f4 wf;
          wf.x = __uint_as_float(u.x << 16);
          wf.y = __uint_as_float(u.x & 0xffff0000u);
          wf.z = __uint_as_float(u.y << 16);
          wf.w = __uint_as_float(u.y & 0xffff0000u);
          fma4(acc[j][0], xb0, wf); fma4(acc[j][1], xb1, wf);
          fma4(acc[j][2], xb2, wf); fma4(acc[j][3], xb3, wf);
        }
      }
      // 32-way k reduction: in-wave xor butterfly over lane bits 0..4
#pragma unroll
      for (int j = 0; j < 4; ++j)
#pragma unroll
        for (int b2 = 0; b2 < 4; ++b2) {
          float v = acc[j][b2];
          v += __shfl_xor(v, 1, 64);
          v += __shfl_xor(v, 2, 64);
          v += __shfl_xor(v, 4, 64);
          v += __shfl_xor(v, 8, 64);
          v += __shfl_xor(v, 16, 64);
          acc[j][b2] = v;
        }
      if ((tid & 31) == 0) {
#pragma unroll
        for (int j = 0; j < 4; ++j)
#pragma unroll
          for (int b2 = 0; b2 < 4; ++b2)
            gbuf[((b2 << 2) + gt) * 17 + (cq << 2) + j] = acc[j][b2];
      }
      __syncthreads();
      // LSTM cell (wave 0 only) + h publish
      if (tid < 64) {
        const int b2 = tid >> 4, cl = tid & 15;
        const float ig = gbuf[((b2 << 2) + 0) * 17 + cl] + bias_s[cl];
        const float fg = gbuf[((b2 << 2) + 1) * 17 + cl] + bias_s[16 + cl];
        const float gg = gbuf[((b2 << 2) + 2) * 17 + cl] + bias_s[32 + cl];
        const float og = gbuf[((b2 << 2) + 3) * 17 + cl] + bias_s[48 + cl];
        float c = sigm(fg) * c_s[tid] + sigm(ig) * tanhf(gg);
        c_s[tid] = c;
        const float h = sigm(og) * tanhf(c);
        st_sys(h_st + (((size_t)nxt * BB) + B0 + b2) * HH + (rB << 4) + cl, h);
      }
      if (tid == 0)   // release: waits wave-0 vmcnt (covers the 64 h stores)
        __hip_atomic_store(&aslots[(grp << 5) + rB], seq, __ATOMIC_RELEASE,
                           __HIP_MEMORY_SCOPE_AGENT);
    }

    // ---- barrier A (group) : h of all 4 batches ready ----
    if (tid < 32) {
      while (__hip_atomic_load(&aslots[(grp << 5) + tid], __ATOMIC_RELAXED,
                               __HIP_MEMORY_SCOPE_AGENT) < seq)
        __builtin_amdgcn_s_sleep(1);
    }
    __syncthreads();

    // ---- Phase B: 4 blocks per batch (pp<4), d-chunk of 128 each ----
    if (pp < 4) {
      const int b = B0 + bq;
      if (tid < 128) {
        f4 hv2;
        ld1_sys(h_st + (((size_t)nxt * BB) + b) * HH + (tid << 2), hv2);
        *(f4*)&h_s[tid << 2] = hv2;
      }
      __syncthreads();
      // phi = h @ Wg^T + bg  (bf16 Wg, 8 waves x 6 rows)
      {
        const int wv2 = tid >> 6, lane2 = tid & 63;
#pragma unroll
        for (int e = 0; e < 6; ++e) {
          const int r2 = wv2 * 6 + e;
          const unsigned short* wr = Wgb + (r2 << 9) + lane2;
          float pa = 0.f;
#pragma unroll
          for (int j2 = 0; j2 < 8; ++j2)
            pa = fmaf(bf2f(wr[j2 << 6]), h_s[lane2 + (j2 << 6)], pa);
          pa += __shfl_xor(pa, 32, 64); pa += __shfl_xor(pa, 16, 64);
          pa += __shfl_xor(pa, 8, 64);  pa += __shfl_xor(pa, 4, 64);
          pa += __shfl_xor(pa, 2, 64);  pa += __shfl_xor(pa, 1, 64);
          if (lane2 == 0) phi_s[r2] = pa + bgv[r2];
        }
      }
      __syncthreads();
      if (tid < MM) {
        ksi_s[tid] += __expf(phi_s[tid]);
        beta_s[tid] = __expf(phi_s[MM + tid]);
      }
      __syncthreads();
      if (tid == 0) {
        float mx = -1e30f;
        for (int m = 0; m < MM; ++m) mx = fmaxf(mx, phi_s[2 * MM + m]);
        float ssum = 0.f; float ev[MM];
        for (int m = 0; m < MM; ++m) { ev[m] = __expf(phi_s[2 * MM + m] - mx); ssum += ev[m]; }
        const float inv = 1.f / ssum;
        float lo = 1e30f, hi = -1e30f;
        for (int m = 0; m < MM; ++m) {
          alpha_s[m] = ev[m] * inv;
          rbeta_s[m] = 1.f / beta_s[m];
          const float dd = 13.f * beta_s[m] + 3.f;
          lo = fminf(lo, ksi_s[m] - dd);
          hi = fmaxf(hi, ksi_s[m] + dd);
        }
        int ilo = (int)floorf(lo); if (ilo < 0) ilo = 0; if (ilo > SS) ilo = SS;
        int ihi = (int)ceilf(hi) + 1; if (ihi > SS) ihi = SS; if (ihi < ilo) ihi = ilo;
        win_s[0] = ilo; win_s[1] = ihi;
      }
      __syncthreads();
      const int ilo = win_s[0], ihi = win_s[1];
      float* arow = out_align + ((size_t)b * TT + t) * SS;
      for (int s = ilo + tid; s < ihi; s += 512) {
        const float us = (float)s;
        float wsum = 0.f;
#pragma unroll
        for (int m = 0; m < MM; ++m) {
          const float rb2 = rbeta_s[m];
          const float z1 = (us + 1.5f - ksi_s[m]) * rb2;
          const float z0 = (us + 0.5f - ksi_s[m]) * rb2;
          wsum += alpha_s[m] * (sigm(z1) - sigm(z0));
        }
        w_s[s - ilo] = wsum;
        if (pp == 0) arow[s] = wsum;
      }
      __syncthreads();
      // ctx chunk: d in [128*pp, 128*pp+128), 4-way s-split
      {
        const int dl = tid & 127, sg = tid >> 7;
        const int d = (pp << 7) + dl;
        float a3 = 0.f;
        int s = ilo + sg;
        const float* mp = memory + ((size_t)b * SS + s) * HH + d;
        for (; s + 12 < ihi; s += 16, mp += 16 * HH) {
          const float m0 = mp[0], m1 = mp[4 * HH], m2 = mp[8 * HH], m3 = mp[12 * HH];
          a3 = fmaf(w_s[s - ilo], m0, a3);
          a3 = fmaf(w_s[s + 4 - ilo], m1, a3);
          a3 = fmaf(w_s[s + 8 - ilo], m2, a3);
          a3 = fmaf(w_s[s + 12 - ilo], m3, a3);
        }
        for (; s < ihi; s += 4, mp += 4 * HH) a3 = fmaf(w_s[s - ilo], *mp, a3);
        red2[sg * 132 + dl] = a3;
      }
      __syncthreads();
      if (tid < 128) {
        const float cv2 = red2[tid] + red2[132 + tid] + red2[264 + tid] + red2[396 + tid];
        st_sys(ctx_st + (size_t)b * HH + (pp << 7) + tid, cv2);
        const size_t o = ((size_t)b * TT + t) * HH + (pp << 7) + tid;
        out_ctx[o] = cv2 + input[o];
        waitvm0();   // retire sc1 ctx stores (waves 0 and 1) before flag
      }
      __syncthreads();
      if (tid == 0)
        __hip_atomic_store(&bslots[(grp << 4) + (bq << 2) + pp], seq, __ATOMIC_RELEASE,
                           __HIP_MEMORY_SCOPE_AGENT);
    }

    // ---- barrier B (group) : ctx ready ----
    if (tid < 16) {
      while (__hip_atomic_load(&bslots[(grp << 4) + tid], __ATOMIC_RELAXED,
                               __HIP_MEMORY_SCOPE_AGENT) < seq)
        __builtin_amdgcn_s_sleep(1);
    }
    __syncthreads();
  }
}

extern "C" void kernel_launch(void* const* d_in, const int* in_sizes, int n_in,
                              void* d_out, int out_size, void* d_ws, size_t ws_size,
                              hipStream_t stream) {
  const float* input = (const float*)d_in[0];
  const float* memory = (const float*)d_in[1];
  const float* Wih = (const float*)d_in[2];
  const float* Whh = (const float*)d_in[3];
  const float* bih = (const float*)d_in[4];
  const float* bhh = (const float*)d_in[5];
  const float* Wg = (const float*)d_in[6];
  const float* bgv = (const float*)d_in[7];
  float* out_ctx = (float*)d_out;
  float* out_align = out_ctx + (size_t)BB * TT * HH;

  char* ws = (char*)d_ws;
  unsigned* slots = (unsigned*)(ws + WS_ASLOTS);
  unsigned* aslots = slots;
  unsigned* bslots = slots + 256;
  float* ctx_st = (float*)(ws + WS_CTX);
  float* h_st = (float*)(ws + WS_H);
  unsigned short* Wihb = (unsigned short*)(ws + WS_WIHB);
  unsigned short* Whhb = (unsigned short*)(ws + WS_WHHB);
  unsigned short* Wgb = (unsigned short*)(ws + WS_WGB);

  k_init<<<dim3(2048), dim3(256), 0, stream>>>(Wih, Whh, Wg, Wihb, Whhb, Wgb,
                                               out_align, ctx_st, h_st, slots);

  void* args[] = { (void*)&input, (void*)&memory, (void*)&bih, (void*)&bhh, (void*)&bgv,
                   (void*)&Wihb, (void*)&Whhb, (void*)&Wgb,
                   (void*)&out_ctx, (void*)&out_align,
                   (void*)&ctx_st, (void*)&h_st, (void*)&aslots, (void*)&bslots };
  hipLaunchCooperativeKernel((void*)k_main, dim3(256), dim3(512), args, 0, stream);
}

// Round 5
// 9964.140 us; speedup vs baseline: 5.1091x; 1.0867x over previous
//
#include <hip/hip_runtime.h>

#define BB 32
#define TT 512
#define SS 1024
#define HH 512
#define MM 16

typedef float f4 __attribute__((ext_vector_type(4)));

// d_ws layout (bytes)
#define WS_ASLOTS 0          // 256 u32
#define WS_BSLOTS 1024       // 256 u32
#define WS_CTX    2048       // 32*512 f32
#define WS_H      67584      // 2*32*512 f32
#define WS_WIHB   198656     // 2048*1024 bf16 (4 MB)
#define WS_WHHB   4392960    // 2048*512 bf16 (2 MB)
#define WS_WGB    6490112    // 48*512 bf16

#define PADR 640
#define IDXH(k) ((k) + (((k) >> 4) << 2))

__device__ __forceinline__ float sigm(float z) { return 1.f / (1.f + __expf(-z)); }
__device__ __forceinline__ float bf2f(unsigned short u) {
  return __uint_as_float((unsigned)u << 16);
}
__device__ __forceinline__ unsigned short f2bf(float f) {
  unsigned u = __float_as_uint(f);
  return (unsigned short)((u + 0x7fffu + ((u >> 16) & 1u)) >> 16);
}
__device__ __forceinline__ void fma4(float& a, const f4& u, const f4& v) {
  a = fmaf(u.x, v.x, fmaf(u.y, v.y, fmaf(u.z, v.z, fmaf(u.w, v.w, a))));
}

// LLC-coherent wide ops (bypass L1/L2)
__device__ __forceinline__ void ld1_sys(const float* p0, f4& a) {
  asm volatile("global_load_dwordx4 %0, %1, off sc1\n\ts_waitcnt vmcnt(0)"
               : "=&v"(a) : "v"(p0) : "memory");
}
__device__ __forceinline__ void st_sys(float* p, float v) {
  asm volatile("global_store_dword %0, %1, off sc1" :: "v"(p), "v"(v) : "memory");
}

__global__ void k_init(const float* __restrict__ Wih, const float* __restrict__ Whh,
                       const float* __restrict__ Wg,
                       unsigned short* __restrict__ Wihb, unsigned short* __restrict__ Whhb,
                       unsigned short* __restrict__ Wgb,
                       float* __restrict__ out_align, float* __restrict__ ctx_st,
                       float* __restrict__ h_st, unsigned* __restrict__ slots) {
  const size_t idx = (size_t)blockIdx.x * blockDim.x + threadIdx.x;
  const size_t stride = (size_t)gridDim.x * blockDim.x;
  f4 z4 = {0.f, 0.f, 0.f, 0.f};
  for (size_t i = idx; i < (size_t)BB * TT * SS / 4; i += stride) ((f4*)out_align)[i] = z4;
  for (size_t i = idx; i < (size_t)BB * HH / 4; i += stride) ((f4*)ctx_st)[i] = z4;
  for (size_t i = idx; i < (size_t)2 * BB * HH / 4; i += stride) ((f4*)h_st)[i] = z4;
  for (size_t i = idx; i < 512; i += stride) slots[i] = 0u;
  for (size_t i = idx; i < (size_t)2048 * 1024; i += stride) Wihb[i] = f2bf(Wih[i]);
  for (size_t i = idx; i < (size_t)2048 * 512; i += stride) Whhb[i] = f2bf(Whh[i]);
  for (size_t i = idx; i < (size_t)48 * 512; i += stride) Wgb[i] = f2bf(Wg[i]);
}

__launch_bounds__(512)
__global__ void k_main(const float* __restrict__ input, const float* __restrict__ memory,
                       const float* __restrict__ bih, const float* __restrict__ bhh,
                       const float* __restrict__ bgv,
                       const unsigned short* __restrict__ Wihb,
                       const unsigned short* __restrict__ Whhb,
                       const unsigned short* __restrict__ Wgb,
                       float* __restrict__ out_ctx, float* __restrict__ out_align,
                       float* __restrict__ ctx_st, float* __restrict__ h_st,
                       unsigned* __restrict__ aslots, unsigned* __restrict__ bslots) {
  __shared__ float x_lds[4 * PADR];
  __shared__ float c_lds[4 * PADR];
  __shared__ float h_lds[4 * PADR];
  __shared__ float gbuf[16 * 17];
  __shared__ float bias_s[64];
  __shared__ float c_s[64];
  __shared__ float w_s[SS];
  __shared__ float red2[8 * 68];
  __shared__ float phi_s[48];
  __shared__ float alpha_s[MM], rbeta_s[MM], ksi_s[MM], beta_s[MM];
  __shared__ int win_s[2];

  const int tid = threadIdx.x;
  const int bid = blockIdx.x;
  const int grp = bid >> 5;        // 8 groups of 32 blocks; group owns 4 batches
  const int rB  = bid & 31;        // rank in group -> 16 gate-cols
  const int B0  = grp << 2;

  // phase-A thread coords
  const int ks = tid & 31;         // 32-way k split, 16 k each
  const int rq = tid >> 5;
  const int gt = rq >> 2;          // gate
  const int cq = rq & 3;           // col quad
  const int colb = (rB << 4) + (cq << 2);
  const unsigned short* wiB = Wihb + (((size_t)(gt << 9) + colb) << 10) + (ks << 4);
  const unsigned short* whB = Whhb + (((size_t)(gt << 9) + colb) << 9) + (ks << 4);

  // phase-B coords: 8 blocks per batch
  const int bq = rB >> 3;          // batch within group
  const int pp = rB & 7;           // d-chunk (64 wide)
  const int b  = B0 + bq;

  // staging coords
  const int sb = tid >> 7;
  const int sk = (tid & 127) << 2;
  const int ski = IDXH(sk);

  if (tid < 64) {
    const int row = ((tid >> 4) << 9) + (rB << 4) + (tid & 15);
    bias_s[tid] = bih[row] + bhh[row];
    c_s[tid] = 0.f;
  }
  if (tid < MM) ksi_s[tid] = 0.f;
  __syncthreads();

  float acc[4][4];

  // ---- prologue: stage x(0), h(-1)=0; compute x+h parts for t=0 ----
  {
    f4 xv = *(const f4*)(input + ((size_t)(B0 + sb) * TT + 0) * HH + sk);
    f4 hv;
    ld1_sys(h_st + (size_t)(B0 + sb) * HH + sk, hv);   // buffer 0 (zeroed)
    *(f4*)&x_lds[sb * PADR + ski] = xv;
    *(f4*)&h_lds[sb * PADR + ski] = hv;
  }
  __syncthreads();
#pragma unroll
  for (int j = 0; j < 4; ++j)
#pragma unroll
    for (int b2 = 0; b2 < 4; ++b2) acc[j][b2] = 0.f;
#pragma unroll
  for (int i = 0; i < 4; ++i) {
    const int kx = 20 * ks + 4 * i;
    f4 xb0 = *(const f4*)&x_lds[0 * PADR + kx];
    f4 xb1 = *(const f4*)&x_lds[1 * PADR + kx];
    f4 xb2 = *(const f4*)&x_lds[2 * PADR + kx];
    f4 xb3 = *(const f4*)&x_lds[3 * PADR + kx];
    f4 hb0 = *(const f4*)&h_lds[0 * PADR + kx];
    f4 hb1 = *(const f4*)&h_lds[1 * PADR + kx];
    f4 hb2 = *(const f4*)&h_lds[2 * PADR + kx];
    f4 hb3 = *(const f4*)&h_lds[3 * PADR + kx];
#pragma unroll
    for (int j = 0; j < 4; ++j) {
      uint2 u = *(const uint2*)(wiB + (j << 10) + 4 * i);
      f4 wf;
      wf.x = __uint_as_float(u.x << 16); wf.y = __uint_as_float(u.x & 0xffff0000u);
      wf.z = __uint_as_float(u.y << 16); wf.w = __uint_as_float(u.y & 0xffff0000u);
      fma4(acc[j][0], xb0, wf); fma4(acc[j][1], xb1, wf);
      fma4(acc[j][2], xb2, wf); fma4(acc[j][3], xb3, wf);
      uint2 v = *(const uint2*)(whB + (j << 9) + 4 * i);
      f4 wh;
      wh.x = __uint_as_float(v.x << 16); wh.y = __uint_as_float(v.x & 0xffff0000u);
      wh.z = __uint_as_float(v.y << 16); wh.w = __uint_as_float(v.y & 0xffff0000u);
      fma4(acc[j][0], hb0, wh); fma4(acc[j][1], hb1, wh);
      fma4(acc[j][2], hb2, wh); fma4(acc[j][3], hb3, wh);
    }
  }

  for (int t = 0; t < TT; ++t) {
    const unsigned seq = (unsigned)(t + 1);
    const int nxt = (t + 1) & 1;     // buffer holding h(t)

    // ---- wait ctx(t-1) ready, stage it ----
    if (tid < 32) {
      while (__hip_atomic_load(&bslots[(grp << 5) + tid], __ATOMIC_RELAXED,
                               __HIP_MEMORY_SCOPE_AGENT) < (unsigned)t) {}
    }
    __syncthreads();
    {
      f4 cv;
      ld1_sys(ctx_st + (size_t)(B0 + sb) * HH + sk, cv);
      *(f4*)&c_lds[sb * PADR + ski] = cv;
    }
    __syncthreads();

    // ---- ctx-part of gates(t) ----
#pragma unroll
    for (int i = 0; i < 4; ++i) {
      const int kx = 20 * ks + 4 * i;
      f4 cb0 = *(const f4*)&c_lds[0 * PADR + kx];
      f4 cb1 = *(const f4*)&c_lds[1 * PADR + kx];
      f4 cb2 = *(const f4*)&c_lds[2 * PADR + kx];
      f4 cb3 = *(const f4*)&c_lds[3 * PADR + kx];
#pragma unroll
      for (int j = 0; j < 4; ++j) {
        uint2 u = *(const uint2*)(wiB + 512 + (j << 10) + 4 * i);
        f4 wf;
        wf.x = __uint_as_float(u.x << 16); wf.y = __uint_as_float(u.x & 0xffff0000u);
        wf.z = __uint_as_float(u.y << 16); wf.w = __uint_as_float(u.y & 0xffff0000u);
        fma4(acc[j][0], cb0, wf); fma4(acc[j][1], cb1, wf);
        fma4(acc[j][2], cb2, wf); fma4(acc[j][3], cb3, wf);
      }
    }
    // ---- reduce over ks (in-wave butterfly, ks = lane&31) ----
#pragma unroll
    for (int j = 0; j < 4; ++j)
#pragma unroll
      for (int b2 = 0; b2 < 4; ++b2) {
        float v = acc[j][b2];
        v += __shfl_xor(v, 1, 64);
        v += __shfl_xor(v, 2, 64);
        v += __shfl_xor(v, 4, 64);
        v += __shfl_xor(v, 8, 64);
        v += __shfl_xor(v, 16, 64);
        acc[j][b2] = v;
      }
    if ((tid & 31) == 0) {
#pragma unroll
      for (int j = 0; j < 4; ++j)
#pragma unroll
        for (int b2 = 0; b2 < 4; ++b2)
          gbuf[((b2 << 2) + gt) * 17 + (cq << 2) + j] = acc[j][b2];
    }
    __syncthreads();
    // ---- LSTM cell + publish h(t) + flag A ----
    if (tid < 64) {
      const int b2 = tid >> 4, cl = tid & 15;
      const float ig = gbuf[((b2 << 2) + 0) * 17 + cl] + bias_s[cl];
      const float fg = gbuf[((b2 << 2) + 1) * 17 + cl] + bias_s[16 + cl];
      const float gg = gbuf[((b2 << 2) + 2) * 17 + cl] + bias_s[32 + cl];
      const float og = gbuf[((b2 << 2) + 3) * 17 + cl] + bias_s[48 + cl];
      float c = sigm(fg) * c_s[tid] + sigm(ig) * tanhf(gg);
      c_s[tid] = c;
      const float h = sigm(og) * tanhf(c);
      st_sys(h_st + (((size_t)nxt * BB) + B0 + b2) * HH + (rB << 4) + cl, h);
    }
    if (tid == 0)
      __hip_atomic_store(&aslots[(grp << 5) + rB], seq, __ATOMIC_RELEASE,
                         __HIP_MEMORY_SCOPE_AGENT);

    // ---- stage x(t+1) + compute x-part(t+1) (hides barrier-A hop) ----
    {
      const int tload = (t + 1 < TT) ? (t + 1) : t;
      f4 xv = *(const f4*)(input + ((size_t)(B0 + sb) * TT + tload) * HH + sk);
      *(f4*)&x_lds[sb * PADR + ski] = xv;
    }
    __syncthreads();
#pragma unroll
    for (int j = 0; j < 4; ++j)
#pragma unroll
      for (int b2 = 0; b2 < 4; ++b2) acc[j][b2] = 0.f;
#pragma unroll
    for (int i = 0; i < 4; ++i) {
      const int kx = 20 * ks + 4 * i;
      f4 xb0 = *(const f4*)&x_lds[0 * PADR + kx];
      f4 xb1 = *(const f4*)&x_lds[1 * PADR + kx];
      f4 xb2 = *(const f4*)&x_lds[2 * PADR + kx];
      f4 xb3 = *(const f4*)&x_lds[3 * PADR + kx];
#pragma unroll
      for (int j = 0; j < 4; ++j) {
        uint2 u = *(const uint2*)(wiB + (j << 10) + 4 * i);
        f4 wf;
        wf.x = __uint_as_float(u.x << 16); wf.y = __uint_as_float(u.x & 0xffff0000u);
        wf.z = __uint_as_float(u.y << 16); wf.w = __uint_as_float(u.y & 0xffff0000u);
        fma4(acc[j][0], xb0, wf); fma4(acc[j][1], xb1, wf);
        fma4(acc[j][2], xb2, wf); fma4(acc[j][3], xb3, wf);
      }
    }

    // ---- wait barrier A(t); stage h(t) ----
    if (tid < 32) {
      while (__hip_atomic_load(&aslots[(grp << 5) + tid], __ATOMIC_RELAXED,
                               __HIP_MEMORY_SCOPE_AGENT) < seq) {}
    }
    __syncthreads();
    {
      f4 hv;
      ld1_sys(h_st + (((size_t)nxt * BB) + B0 + sb) * HH + sk, hv);
      *(f4*)&h_lds[sb * PADR + ski] = hv;
    }
    __syncthreads();

    // ---- Phase B(t): all blocks; 8 blocks per batch ----
    {
      // phi = h @ Wg^T + bg (replicated across the batch's 8 blocks)
      const int wv2 = tid >> 6, lane2 = tid & 63;
#pragma unroll
      for (int e = 0; e < 6; ++e) {
        const int r2 = wv2 * 6 + e;
        const unsigned short* wr = Wgb + (r2 << 9);
        float pa = 0.f;
#pragma unroll
        for (int j2 = 0; j2 < 8; ++j2) {
          const int k = lane2 + (j2 << 6);
          pa = fmaf(bf2f(wr[k]), h_lds[bq * PADR + IDXH(k)], pa);
        }
        pa += __shfl_xor(pa, 32, 64); pa += __shfl_xor(pa, 16, 64);
        pa += __shfl_xor(pa, 8, 64);  pa += __shfl_xor(pa, 4, 64);
        pa += __shfl_xor(pa, 2, 64);  pa += __shfl_xor(pa, 1, 64);
        if (lane2 == 0) phi_s[r2] = pa + bgv[r2];
      }
    }
    __syncthreads();
    if (tid < MM) {
      ksi_s[tid] += __expf(phi_s[tid]);
      beta_s[tid] = __expf(phi_s[MM + tid]);
    }
    __syncthreads();
    if (tid == 0) {
      float mx = -1e30f;
      for (int m = 0; m < MM; ++m) mx = fmaxf(mx, phi_s[2 * MM + m]);
      float ssum = 0.f; float ev[MM];
      for (int m = 0; m < MM; ++m) { ev[m] = __expf(phi_s[2 * MM + m] - mx); ssum += ev[m]; }
      const float inv = 1.f / ssum;
      float lo = 1e30f, hi = -1e30f;
      for (int m = 0; m < MM; ++m) {
        alpha_s[m] = ev[m] * inv;
        rbeta_s[m] = 1.f / beta_s[m];
        const float dd = 13.f * beta_s[m] + 3.f;
        lo = fminf(lo, ksi_s[m] - dd);
        hi = fmaxf(hi, ksi_s[m] + dd);
      }
      int ilo = (int)floorf(lo); if (ilo < 0) ilo = 0; if (ilo > SS) ilo = SS;
      int ihi = (int)ceilf(hi) + 1; if (ihi > SS) ihi = SS; if (ihi < ilo) ihi = ilo;
      win_s[0] = ilo; win_s[1] = ihi;
    }
    __syncthreads();
    const int ilo = win_s[0], ihi = win_s[1];
    {
      float* arow = out_align + ((size_t)b * TT + t) * SS;
      for (int s = ilo + tid; s < ihi; s += 512) {
        const float us = (float)s;
        float wsum = 0.f;
#pragma unroll
        for (int m = 0; m < MM; ++m) {
          const float rb2 = rbeta_s[m];
          const float z1 = (us + 1.5f - ksi_s[m]) * rb2;
          const float z0 = (us + 0.5f - ksi_s[m]) * rb2;
          wsum += alpha_s[m] * (sigm(z1) - sigm(z0));
        }
        w_s[s - ilo] = wsum;
        if (pp == 0) arow[s] = wsum;
      }
    }
    __syncthreads();
    {
      // ctx chunk: d in [64*pp, 64*pp+64), 8-way s-split
      const int dl = tid & 63, sg = tid >> 6;
      const int d = (pp << 6) + dl;
      float a3 = 0.f;
      int s = ilo + sg;
      const float* mp = memory + ((size_t)b * SS + s) * HH + d;
      for (; s + 24 < ihi; s += 32, mp += 32 * HH) {
        const float m0 = mp[0], m1 = mp[8 * HH], m2 = mp[16 * HH], m3 = mp[24 * HH];
        a3 = fmaf(w_s[s - ilo], m0, a3);
        a3 = fmaf(w_s[s + 8 - ilo], m1, a3);
        a3 = fmaf(w_s[s + 16 - ilo], m2, a3);
        a3 = fmaf(w_s[s + 24 - ilo], m3, a3);
      }
      for (; s < ihi; s += 8, mp += 8 * HH) a3 = fmaf(w_s[s - ilo], *mp, a3);
      red2[sg * 68 + dl] = a3;
    }
    __syncthreads();
    if (tid < 64) {
      float cv = 0.f;
#pragma unroll
      for (int g2 = 0; g2 < 8; ++g2) cv += red2[g2 * 68 + tid];
      st_sys(ctx_st + (size_t)b * HH + (pp << 6) + tid, cv);
      const size_t o = ((size_t)b * TT + t) * HH + (pp << 6) + tid;
      out_ctx[o] = cv + input[o];
    }
    if (tid == 0)
      __hip_atomic_store(&bslots[(grp << 5) + rB], seq, __ATOMIC_RELEASE,
                         __HIP_MEMORY_SCOPE_AGENT);

    // ---- h-part(t+1) (hides barrier-B hop + other blocks' B work) ----
    if (t + 1 < TT) {
#pragma unroll
      for (int i = 0; i < 4; ++i) {
        const int kx = 20 * ks + 4 * i;
        f4 hb0 = *(const f4*)&h_lds[0 * PADR + kx];
        f4 hb1 = *(const f4*)&h_lds[1 * PADR + kx];
        f4 hb2 = *(const f4*)&h_lds[2 * PADR + kx];
        f4 hb3 = *(const f4*)&h_lds[3 * PADR + kx];
#pragma unroll
        for (int j = 0; j < 4; ++j) {
          uint2 v = *(const uint2*)(whB + (j << 9) + 4 * i);
          f4 wh;
          wh.x = __uint_as_float(v.x << 16); wh.y = __uint_as_float(v.x & 0xffff0000u);
          wh.z = __uint_as_float(v.y << 16); wh.w = __uint_as_float(v.y & 0xffff0000u);
          fma4(acc[j][0], hb0, wh); fma4(acc[j][1], hb1, wh);
          fma4(acc[j][2], hb2, wh); fma4(acc[j][3], hb3, wh);
        }
      }
    }
  }
}

extern "C" void kernel_launch(void* const* d_in, const int* in_sizes, int n_in,
                              void* d_out, int out_size, void* d_ws, size_t ws_size,
                              hipStream_t stream) {
  const float* input = (const float*)d_in[0];
  const float* memory = (const float*)d_in[1];
  const float* Wih = (const float*)d_in[2];
  const float* Whh = (const float*)d_in[3];
  const float* bih = (const float*)d_in[4];
  const float* bhh = (const float*)d_in[5];
  const float* Wg = (const float*)d_in[6];
  const float* bgv = (const float*)d_in[7];
  float* out_ctx = (float*)d_out;
  float* out_align = out_ctx + (size_t)BB * TT * HH;

  char* ws = (char*)d_ws;
  unsigned* slots = (unsigned*)(ws + WS_ASLOTS);
  unsigned* aslots = slots;
  unsigned* bslots = slots + 256;
  float* ctx_st = (float*)(ws + WS_CTX);
  float* h_st = (float*)(ws + WS_H);
  unsigned short* Wihb = (unsigned short*)(ws + WS_WIHB);
  unsigned short* Whhb = (unsigned short*)(ws + WS_WHHB);
  unsigned short* Wgb = (unsigned short*)(ws + WS_WGB);

  k_init<<<dim3(2048), dim3(256), 0, stream>>>(Wih, Whh, Wg, Wihb, Whhb, Wgb,
                                               out_align, ctx_st, h_st, slots);

  void* args[] = { (void*)&input, (void*)&memory, (void*)&bih, (void*)&bhh, (void*)&bgv,
                   (void*)&Wihb, (void*)&Whhb, (void*)&Wgb,
                   (void*)&out_ctx, (void*)&out_align,
                   (void*)&ctx_st, (void*)&h_st, (void*)&aslots, (void*)&bslots };
  hipLaunchCooperativeKernel((void*)k_main, dim3(256), dim3(512), args, 0, stream);
}